// Round 6
// baseline (108.516 us; speedup 1.0000x reference)
//
#include <hip/hip_runtime.h>

#define BB 32
#define SS 2048
#define DD 1024

typedef float f32x4 __attribute__((ext_vector_type(4)));

#if defined(__has_builtin)
#  if __has_builtin(__builtin_amdgcn_exp2f)
#    define EXP2F(x) __builtin_amdgcn_exp2f(x)
#  endif
#  if __has_builtin(__builtin_amdgcn_rcpf)
#    define RCPF(x) __builtin_amdgcn_rcpf(x)
#  endif
#endif
#ifndef EXP2F
#  define EXP2F(x) exp2f(x)
#endif
#ifndef RCPF
#  define RCPF(x) (1.0f / (x))
#endif

#define LOG2E 1.44269504088896340736f

__device__ __forceinline__ float fast_tanh(float x) {
    x = fminf(fmaxf(x, -20.0f), 20.0f);
    float e = EXP2F(x * (2.0f * LOG2E));
    return (e - 1.0f) * RCPF(e + 1.0f);
}

__device__ __forceinline__ f32x4 ntload4(const float* p) {
    return __builtin_nontemporal_load((const f32x4*)p);
}

// ---------------- K1: dec_feature = dec_hidden @ W^T + b; zero ctx ----------------
// Reg-tiled: 128 blocks x 8 columns. Thread = (column-group cg, lane32).
// W slice (32 floats) held in VGPRs -> W read from HBM exactly once (4 MB).
// Loop over 32 batches; dh row (4 KB) L1-broadcast across the 8 column groups.
__global__ __launch_bounds__(256) void k_decfeat(
    const float* __restrict__ dh, const float* __restrict__ W,
    const float* __restrict__ bd, float* __restrict__ df,
    float* __restrict__ ctx) {
    if (blockIdx.x < BB) {
        f32x4 z = {0.f, 0.f, 0.f, 0.f};
        ((f32x4*)ctx)[blockIdx.x * 256 + threadIdx.x] = z;
    }
    int t = threadIdx.x;
    int cg = t >> 5, lane32 = t & 31;
    int i = blockIdx.x * 8 + cg;            // output column 0..1023
    const float* wrow = W + (size_t)i * DD;
    f32x4 w[8];
#pragma unroll
    for (int j = 0; j < 8; ++j)
        w[j] = *(const f32x4*)(wrow + lane32 * 4 + 128 * j);
    float bi = bd[i];
    for (int b = 0; b < BB; ++b) {
        const float* drow = dh + (size_t)b * DD;
        f32x4 acc4 = {0.f, 0.f, 0.f, 0.f};
#pragma unroll
        for (int j = 0; j < 8; ++j) {
            f32x4 d = *(const f32x4*)(drow + lane32 * 4 + 128 * j);
            acc4 += w[j] * d;
        }
        float acc = acc4.x + acc4.y + acc4.z + acc4.w;
#pragma unroll
        for (int off = 16; off; off >>= 1) acc += __shfl_down(acc, off, 32);
        if (lane32 == 0) df[(size_t)b * DD + i] = acc + bi;
    }
}

// ---------------- K2: E[b,s] = exp(v . tanh(ef + df + cov*wc)) ----------------
// Proven (R3/R5): no max-subtraction (|score| <= ||v||_1 ~ 26, f32-safe);
// softmax denominator cancels in the mask renormalization.
__global__ __launch_bounds__(256) void k_score(
    const float* __restrict__ ef, const float* __restrict__ df,
    const float* __restrict__ cov, const float* __restrict__ v,
    const float* __restrict__ wc, float* __restrict__ E) {
    int b  = blockIdx.x >> 8;               // 256 tiles per batch
    int s0 = (blockIdx.x & 255) * 8;
    int t  = threadIdx.x;
    float4 v4 = ((const float4*)v)[t];
    float4 w4 = ((const float4*)wc)[t];
    float4 d4 = ((const float4*)(df + (size_t)b * DD))[t];
    float part[8];
#pragma unroll
    for (int k = 0; k < 8; ++k) {
        int s = s0 + k;
        float c = cov[b * SS + s];
        f32x4 e4 = ntload4(ef + ((size_t)b * SS + s) * DD + t * 4);
        float t0 = fast_tanh(e4.x + d4.x + c * w4.x);
        float t1 = fast_tanh(e4.y + d4.y + c * w4.y);
        float t2 = fast_tanh(e4.z + d4.z + c * w4.z);
        float t3 = fast_tanh(e4.w + d4.w + c * w4.w);
        part[k] = v4.x * t0 + v4.y * t1 + v4.z * t2 + v4.w * t3;
    }
    __shared__ float red[4][8];
    int lane = t & 63, wave = t >> 6;
#pragma unroll
    for (int k = 0; k < 8; ++k) {
        float p = part[k];
#pragma unroll
        for (int off = 32; off; off >>= 1) p += __shfl_down(p, off, 64);
        if (lane == 0) red[wave][k] = p;
    }
    __syncthreads();
    if (t < 8) {
        float sc = red[0][t] + red[1][t] + red[2][t] + red[3][t];
        E[b * SS + s0 + t] = EXP2F(sc * LOG2E);
    }
}

// ---------------- K4: inv (redundant row-reduce) + attn/covnew + context ----------------
// Proven (R5). block = (b, 64-row chunk). Prologue reduces the FULL E*mask row
// (L2-resident, 32x redundant) -> inv locally; epilogue atomicAdds the chunk's
// context partial into ctx (spread over 2048 cache lines, <=32 writers each).
__global__ __launch_bounds__(256) void k_ctx_part(
    const float* __restrict__ eo, const float* __restrict__ E,
    const float* __restrict__ mask, const float* __restrict__ cov,
    float* __restrict__ attn, float* __restrict__ covnew,
    float* __restrict__ ctx) {
    int b = blockIdx.x >> 5, ch = blockIdx.x & 31;
    int t = threadIdx.x;
    int lane = t & 63, wave = t >> 6;
    // --- inv[b] ---
    float sum = 0.0f;
#pragma unroll
    for (int k = 0; k < 8; ++k) {
        int s = t + 256 * k;
        sum += E[b * SS + s] * mask[b * SS + s];
    }
#pragma unroll
    for (int off = 32; off; off >>= 1) sum += __shfl_down(sum, off, 64);
    __shared__ float red[4];
    __shared__ float invs;
    if (lane == 0) red[wave] = sum;
    __syncthreads();
    if (t == 0) invs = RCPF(red[0] + red[1] + red[2] + red[3]);
    __syncthreads();
    // --- attn/covnew for own chunk ---
    int s0 = ch * 64;
    __shared__ float als[64];
    if (t < 64) {
        int s = s0 + t;
        float a = E[b * SS + s] * mask[b * SS + s] * invs;
        attn[b * SS + s] = a;
        covnew[b * SS + s] = cov[b * SS + s] + a;
        als[t] = a;
    }
    __syncthreads();
    // --- stream enc_output chunk ---
    const float* base = eo + ((size_t)b * SS + s0) * DD;
    f32x4 acc = {0.f, 0.f, 0.f, 0.f};
#pragma unroll 8
    for (int k = 0; k < 64; ++k) {
        f32x4 e4 = ntload4(base + (size_t)k * DD + t * 4);
        acc += als[k] * e4;
    }
    float* cp = ctx + (size_t)b * DD + t * 4;
    atomicAdd(cp + 0, acc.x);
    atomicAdd(cp + 1, acc.y);
    atomicAdd(cp + 2, acc.z);
    atomicAdd(cp + 3, acc.w);
}

extern "C" void kernel_launch(void* const* d_in, const int* in_sizes, int n_in,
                              void* d_out, int out_size, void* d_ws, size_t ws_size,
                              hipStream_t stream) {
    const float* dec_hidden  = (const float*)d_in[0];
    const float* enc_output  = (const float*)d_in[1];
    const float* enc_feature = (const float*)d_in[2];
    const float* enc_mask    = (const float*)d_in[3];
    // d_in[4] = sec_attn (unused by reference outputs)
    const float* coverage    = (const float*)d_in[5];
    const float* W_dec       = (const float*)d_in[6];
    const float* b_dec       = (const float*)d_in[7];
    const float* v           = (const float*)d_in[8];
    const float* w_cov       = (const float*)d_in[9];

    float* ctx    = (float*)d_out;                     // [B, DIM]   32768
    float* attn   = (float*)d_out + BB * DD;           // [B, S]     65536
    float* covnew = (float*)d_out + BB * DD + BB * SS; // [B, S]     65536

    char* ws = (char*)d_ws;
    float* df = (float*)(ws);                          // 128 KiB
    float* E  = (float*)(ws + 131072);                 // 256 KiB

    k_decfeat  <<<128,   256, 0, stream>>>(dec_hidden, W_dec, b_dec, df, ctx);
    k_score    <<<8192,  256, 0, stream>>>(enc_feature, df, coverage, v, w_cov, E);
    k_ctx_part <<<BB*32, 256, 0, stream>>>(enc_output, E, enc_mask, coverage,
                                           attn, covnew, ctx);
}